// Round 1
// 625.417 us; speedup vs baseline: 1.3704x; 1.3704x over previous
//
#include <hip/hip_runtime.h>

using u16 = unsigned short;
using f32x4 = __attribute__((ext_vector_type(4))) float;
using s16x8 = __attribute__((ext_vector_type(8))) short;
using u32x4 = __attribute__((ext_vector_type(4))) unsigned int;

// ---- problem constants (T=512, B=64, D=256, H=256) ----
#define TT 512
#define BB 64
#define ALPHA 0.9f
// output element offsets (FP32 elements) in d_out, concatenated return order:
// spikes [513,64,256], preds [512,64,256], probs [512,64,256], v_T [64,256], s_T [64,256]
#define SPIKES_OFF 0L
#define PREDS_OFF  8404992L
#define PROBS_OFF  16793600L
#define VT_OFF     25182208L
#define ST_OFF     25198592L

__device__ __forceinline__ u16 f2bf(float f) {
    union { float f; unsigned int i; } cv; cv.f = f;
    unsigned int x = cv.i;
    return (u16)((x + 0x7FFFu + ((x >> 16) & 1u)) >> 16);   // RNE
}

// Packed RNE fp32x2 -> bf16x2 in ONE instruction (no builtin on gfx950; m240).
__device__ __forceinline__ unsigned int cvt_pk_bf16(float lo, float hi) {
    unsigned int r;
    asm("v_cvt_pk_bf16_f32 %0, %1, %2" : "=v"(r) : "v"(lo), "v"(hi));
    return r;
}

// LDS-only barrier: waits ds ops, NOT the in-flight global stores/loads.
// __syncthreads() would emit s_waitcnt vmcnt(0) and drain every global store
// + prefetch each step (~1500-2000 cyc/step stall, round-5 counters).
__device__ __forceinline__ void lds_barrier() {
    __asm__ volatile("s_waitcnt lgkmcnt(0)\n\ts_barrier" ::: "memory");
}

// ---------------------------------------------------------------------------
// One-time: WT[mat] bf16 [n][k] <- W fp32 [k][n], for W_in / W_rec / W_out.
// ---------------------------------------------------------------------------
__global__ void transpose_w(const float* __restrict__ W_in,
                            const float* __restrict__ W_rec,
                            const float* __restrict__ W_out,
                            u16* __restrict__ WT)
{
    const float* src = (blockIdx.x == 0) ? W_in : (blockIdx.x == 1) ? W_rec : W_out;
    u16* dst = WT + (long)blockIdx.x * 65536;
    const int n = threadIdx.x;
    for (int k0 = 0; k0 < 256; k0 += 8) {
        unsigned int dw[4];
        #pragma unroll
        for (int j = 0; j < 4; ++j)
            dw[j] = cvt_pk_bf16(src[(k0 + 2*j)*256 + n], src[(k0 + 2*j + 1)*256 + n]);
        u32x4 val = { dw[0], dw[1], dw[2], dw[3] };
        *(u32x4*)&dst[n*256 + k0] = val;
    }
}

// ---------------------------------------------------------------------------
// GEMM: C[m][n] = sum_k A[m][k] * W[k][n] (+ bias[n]).  A fp32 -> bf16 LDS,
// WT bf16 [n][k] -> dwordx4 fragment loads.  C fp32.
// COPY_A: also mirror the raw A tile to copyDst (used by gemm2 to materialize
// spikes[1:] = probs while it reads them anyway -- removes 4 stores/step from
// the critical recurrence kernel).
// mfma(wfrag, xfrag, acc) -> lane holds D[m = mbase+(lane&15)][n = nbase+quad*4+r].
// wg 256 thr = 4 waves; tile M=64, all N=256; wave w -> n in [w*64, w*64+64).
// ---------------------------------------------------------------------------
template <bool ADD_BIAS, bool COPY_A>
__global__ __launch_bounds__(256, 2)
void gemm_rows(const float* __restrict__ A, const u16* __restrict__ WT,
               const float* __restrict__ bias, float* __restrict__ C,
               float* __restrict__ copyDst)
{
    const int tid  = threadIdx.x;
    const int lane = tid & 63;
    const int wave = tid >> 6;
    const int l15  = lane & 15;
    const int quad = lane >> 4;
    const long mblock = (long)blockIdx.x * 64;

    __shared__ u16 Alds[64][264];   // bf16 tile, +8 pad per row

    #pragma unroll
    for (int i = 0; i < 16; ++i) {
        int q = i*256 + tid;
        int r = q >> 6;
        int c = (q & 63) << 2;
        f32x4 a4 = *(const f32x4*)&A[(mblock + r)*256 + c];
        if (COPY_A)
            *(f32x4*)&copyDst[(mblock + r)*256 + c] = a4;
        uint2 val;
        val.x = cvt_pk_bf16(a4[0], a4[1]);
        val.y = cvt_pk_bf16(a4[2], a4[3]);
        *(uint2*)&Alds[r][c] = val;
    }

    s16x8 wfrag[4][8];
    const int nbase = wave * 64;
    #pragma unroll
    for (int nt = 0; nt < 4; ++nt)
        #pragma unroll
        for (int kt = 0; kt < 8; ++kt)
            wfrag[nt][kt] = *(const s16x8*)&WT[(nbase + nt*16 + l15)*256 + kt*32 + quad*8];

    __syncthreads();

    f32x4 acc[4][4] = {};   // [mt][nt]
    #pragma unroll
    for (int kt = 0; kt < 8; ++kt) {
        s16x8 xfrag[4];
        #pragma unroll
        for (int mt = 0; mt < 4; ++mt)
            xfrag[mt] = *(const s16x8*)&Alds[mt*16 + l15][kt*32 + quad*8];
        #pragma unroll
        for (int mt = 0; mt < 4; ++mt)
            #pragma unroll
            for (int nt = 0; nt < 4; ++nt)
                acc[mt][nt] = __builtin_amdgcn_mfma_f32_16x16x32_bf16(
                    wfrag[nt][kt], xfrag[mt], acc[mt][nt], 0, 0, 0);
    }

    #pragma unroll
    for (int mt = 0; mt < 4; ++mt) {
        long m = mblock + mt*16 + l15;
        #pragma unroll
        for (int nt = 0; nt < 4; ++nt) {
            int n = nbase + nt*16 + quad*4;
            f32x4 r = acc[mt][nt];
            if (ADD_BIAS) {
                f32x4 bb = *(const f32x4*)&bias[n];
                r[0] += bb[0]; r[1] += bb[1]; r[2] += bb[2]; r[3] += bb[3];
            }
            *(f32x4*)&C[m*256 + n] = r;
        }
    }
}

// ---------------------------------------------------------------------------
// MFMA recurrence. 4 WGs x 256 thr (4 waves); WG = 16 batches [B0, B0+16).
// Per step: v = alpha*v + xin + s @ W_rec ; s = sigmoid(v).
// Lane holds D[n = nbase+nt*16+quad*4+r][batch = lane&15] (HW-verified r4).
// s ping-pong in LDS (bf16), ONE raw lds_barrier per step; global stores are
// never waited on; xin prefetched 2 steps ahead (unroll-by-2 ping-pong regs).
// This round: only probs written per step (spikes[1:] materialized by gemm2's
// COPY_A), packed bf16 via v_cvt_pk_bf16_f32, walking pointers with imm
// offsets instead of per-step (t*BB+..)*256 arithmetic, s_T recomputed after
// the loop (no per-step t==TT-1 branch), prefetch issued before the consume.
// ---------------------------------------------------------------------------
__global__ __launch_bounds__(256, 1)
void recurrence_mfma(const float* __restrict__ Xin, const float* __restrict__ spike0,
                     const float* __restrict__ v0, const u16* __restrict__ WTrec,
                     float* __restrict__ out)
{
    const int tid  = threadIdx.x;
    const int lane = tid & 63;
    const int wave = tid >> 6;
    const int l15  = lane & 15;
    const int quad = lane >> 4;
    const int B0   = blockIdx.x * 16;
    const int nbase = wave * 64;
    const int hq = quad * 4;

    __shared__ u16 s_lds[2][16][264];     // [buf][batch][h]

    // W_rec^T A-fragments, register-resident for all 512 steps
    s16x8 wfrag[4][8];
    #pragma unroll
    for (int nt = 0; nt < 4; ++nt)
        #pragma unroll
        for (int kt = 0; kt < 8; ++kt)
            wfrag[nt][kt] = *(const s16x8*)&WTrec[(nbase + nt*16 + l15)*256 + kt*32 + quad*8];

    // init s buffer 0 from spike0; emit spikes[0]
    #pragma unroll
    for (int i = 0; i < 16; ++i) {
        int idx = i*256 + tid;
        int m = idx >> 8, h = idx & 255;
        float s0v = spike0[(B0 + m)*256 + h];
        out[SPIKES_OFF + (B0 + m)*256 + h] = s0v;
        s_lds[0][m][h] = f2bf(s0v);
    }

    const long lrow = (long)(B0 + l15) * 256;
    f32x4 v[4], xinA[4], xinB[4];
    #pragma unroll
    for (int nt = 0; nt < 4; ++nt) {
        const int h = nbase + nt*16 + hq;
        v[nt]    = *(const f32x4*)&v0[lrow + h];
        xinA[nt] = *(const f32x4*)&Xin[lrow + h];           // t=0
        xinB[nt] = *(const f32x4*)&Xin[16384 + lrow + h];   // t=1
    }
    // walking pointers: one 64-bit bump (+64 KB) per half-step; nt -> imm offset.
    const float* xin_p = Xin + 2L*16384 + lrow + nbase + hq;   // prefetch t=2
    float*       pr_p  = out + PROBS_OFF + lrow + nbase + hq;  // probs t=0

    __syncthreads();   // one-time full barrier (covers spike0 LDS init)

    #pragma unroll 1
    for (int t2 = 0; t2 < TT; t2 += 2) {
        #pragma unroll
        for (int half = 0; half < 2; ++half) {
            const int rb = half, wb = half ^ 1;   // t2 even -> (t&1) == half

            // issue prefetch for t+2 FIRST (vmcnt decoupling: the consume-wait
            // 2 steps later then tolerates all intervening stores in flight).
            // Final-iteration over-read (t=512,513) lands in the probs region:
            // valid memory, never consumed.
            f32x4 xnew[4];
            #pragma unroll
            for (int nt = 0; nt < 4; ++nt)
                xnew[nt] = *(const f32x4*)&xin_p[nt*16];

            // s B-fragments from LDS: lane: batch=l15, k = kt*32+quad*8+j
            s16x8 sfrag[8];
            #pragma unroll
            for (int kt = 0; kt < 8; ++kt)
                sfrag[kt] = *(const s16x8*)&s_lds[rb][l15][kt*32 + quad*8];

            // acc = alpha*v + xin (consume this step's 2-ahead prefetch)
            f32x4 acc[4];
            #pragma unroll
            for (int nt = 0; nt < 4; ++nt)
                #pragma unroll
                for (int c = 0; c < 4; ++c)
                    acc[nt][c] = fmaf(ALPHA, v[nt][c],
                                      half == 0 ? xinA[nt][c] : xinB[nt][c]);
            #pragma unroll
            for (int nt = 0; nt < 4; ++nt) {
                if (half == 0) xinA[nt] = xnew[nt]; else xinB[nt] = xnew[nt];
            }

            // accumulate s @ W_rec
            #pragma unroll
            for (int kt = 0; kt < 8; ++kt)
                #pragma unroll
                for (int nt = 0; nt < 4; ++nt)
                    acc[nt] = __builtin_amdgcn_mfma_f32_16x16x32_bf16(
                        wfrag[nt][kt], sfrag[kt], acc[nt], 0, 0, 0);

            // sigmoid, state, probs (spikes[t+1] == probs[t]: written by gemm2)
            #pragma unroll
            for (int nt = 0; nt < 4; ++nt) {
                const int h = nbase + nt*16 + hq;
                f32x4 p;
                #pragma unroll
                for (int c = 0; c < 4; ++c)
                    p[c] = __builtin_amdgcn_rcpf(1.0f + __expf(-acc[nt][c]));
                v[nt] = acc[nt];
                uint2 sw;
                sw.x = cvt_pk_bf16(p[0], p[1]);
                sw.y = cvt_pk_bf16(p[2], p[3]);
                *(uint2*)&s_lds[wb][l15][h] = sw;
                *(f32x4*)&pr_p[nt*16] = p;
            }
            xin_p += 16384;
            pr_p  += 16384;
            lds_barrier();   // LDS-only: no vmcnt drain of stores/prefetch
        }
    }

    // tails: v_T and s_T = sigmoid(v_T) (recomputed once; kills per-step branch)
    #pragma unroll
    for (int nt = 0; nt < 4; ++nt) {
        const int h = nbase + nt*16 + hq;
        f32x4 vv = v[nt], p;
        #pragma unroll
        for (int c = 0; c < 4; ++c)
            p[c] = __builtin_amdgcn_rcpf(1.0f + __expf(-vv[c]));
        *(f32x4*)&out[VT_OFF + lrow + h] = vv;
        *(f32x4*)&out[ST_OFF + lrow + h] = p;
    }
}

// ---------------------------------------------------------------------------
extern "C" void kernel_launch(void* const* d_in, const int* in_sizes, int n_in,
                              void* d_out, int out_size, void* d_ws, size_t ws_size,
                              hipStream_t stream) {
    const float* inputs = (const float*)d_in[0];   // [512,64,256]
    const float* spike0 = (const float*)d_in[1];   // [64,256]
    const float* v0     = (const float*)d_in[2];   // [64,256]
    const float* W_in   = (const float*)d_in[3];   // [256,256]
    const float* W_rec  = (const float*)d_in[4];   // [256,256]
    const float* W_out  = (const float*)d_in[5];   // [256,256]
    const float* bvec   = (const float*)d_in[6];   // [256]
    float* out = (float*)d_out;

    // d_ws: 3 transposed bf16 weight matrices, 384 KB.
    u16* WT = (u16*)d_ws;
    u16* WTin  = WT;
    u16* WTrec = WT + 65536;
    u16* WTout = WT + 131072;

    // Xin (fp32 [32768,256]) staged in the preds output region; overwritten by
    // gemm2 after the recurrence consumes it.
    float* Xin = out + PREDS_OFF;

    transpose_w<<<3, 256, 0, stream>>>(W_in, W_rec, W_out, WT);
    gemm_rows<true, false><<<512, 256, 0, stream>>>(inputs, WTin, bvec, Xin, nullptr);
    recurrence_mfma<<<4, 256, 0, stream>>>(Xin, spike0, v0, WTrec, out);
    // gemm2 reads probs as A (== spikes[1:]) and mirrors the tile into the
    // spikes region while staging it -- recurrence no longer writes spikes.
    gemm_rows<false, true><<<512, 256, 0, stream>>>(out + PROBS_OFF, WTout, bvec,
                                                    out + PREDS_OFF, out + 16384);
}

// Round 2
// 554.984 us; speedup vs baseline: 1.5444x; 1.1269x over previous
//
#include <hip/hip_runtime.h>

using u16 = unsigned short;
using f32x4 = __attribute__((ext_vector_type(4))) float;
using s16x8 = __attribute__((ext_vector_type(8))) short;
using u32x4 = __attribute__((ext_vector_type(4))) unsigned int;

// ---- problem constants (T=512, B=64, D=256, H=256) ----
#define TT 512
#define BB 64
#define ALPHA 0.9f
// output element offsets (FP32 elements) in d_out, concatenated return order:
// spikes [513,64,256], preds [512,64,256], probs [512,64,256], v_T [64,256], s_T [64,256]
#define SPIKES_OFF 0L
#define PREDS_OFF  8404992L
#define PROBS_OFF  16793600L
#define VT_OFF     25182208L
#define ST_OFF     25198592L

__device__ __forceinline__ u16 f2bf(float f) {
    union { float f; unsigned int i; } cv; cv.f = f;
    unsigned int x = cv.i;
    return (u16)((x + 0x7FFFu + ((x >> 16) & 1u)) >> 16);   // RNE
}

// Packed RNE fp32x2 -> bf16x2 in ONE instruction (no builtin on gfx950; m240).
__device__ __forceinline__ unsigned int cvt_pk_bf16(float lo, float hi) {
    unsigned int r;
    asm("v_cvt_pk_bf16_f32 %0, %1, %2" : "=v"(r) : "v"(lo), "v"(hi));
    return r;
}

// LDS-only barrier: waits ds ops, NOT the in-flight global stores/loads.
// __syncthreads() would emit s_waitcnt vmcnt(0) and drain every global store
// + prefetch each step (~1500-2000 cyc/step stall, round-5 counters).
__device__ __forceinline__ void lds_barrier() {
    __asm__ volatile("s_waitcnt lgkmcnt(0)\n\ts_barrier" ::: "memory");
}

// ---------------------------------------------------------------------------
// One-time: WT[mat] bf16 [n][k] <- W fp32 [k][n], for W_in / W_rec / W_out.
// ---------------------------------------------------------------------------
__global__ void transpose_w(const float* __restrict__ W_in,
                            const float* __restrict__ W_rec,
                            const float* __restrict__ W_out,
                            u16* __restrict__ WT)
{
    const float* src = (blockIdx.x == 0) ? W_in : (blockIdx.x == 1) ? W_rec : W_out;
    u16* dst = WT + (long)blockIdx.x * 65536;
    const int n = threadIdx.x;
    for (int k0 = 0; k0 < 256; k0 += 8) {
        unsigned int dw[4];
        #pragma unroll
        for (int j = 0; j < 4; ++j)
            dw[j] = cvt_pk_bf16(src[(k0 + 2*j)*256 + n], src[(k0 + 2*j + 1)*256 + n]);
        u32x4 val = { dw[0], dw[1], dw[2], dw[3] };
        *(u32x4*)&dst[n*256 + k0] = val;
    }
}

// ---------------------------------------------------------------------------
// GEMM: C[m][n] = sum_k A[m][k] * W[k][n] (+ bias[n]).  A fp32 -> bf16 LDS,
// WT bf16 [n][k] -> dwordx4 fragment loads.  C fp32.
// COPY_A: also mirror the raw A tile to copyDst (used by gemm2 to materialize
// spikes[1:] = probs while it reads them anyway -- removes 4 stores/step from
// the critical recurrence kernel).
// mfma(wfrag, xfrag, acc) -> lane holds D[m = mbase+(lane&15)][n = nbase+quad*4+r].
// wg 256 thr = 4 waves; tile M=64, all N=256; wave w -> n in [w*64, w*64+64).
// ---------------------------------------------------------------------------
template <bool ADD_BIAS, bool COPY_A>
__global__ __launch_bounds__(256, 2)
void gemm_rows(const float* __restrict__ A, const u16* __restrict__ WT,
               const float* __restrict__ bias, float* __restrict__ C,
               float* __restrict__ copyDst)
{
    const int tid  = threadIdx.x;
    const int lane = tid & 63;
    const int wave = tid >> 6;
    const int l15  = lane & 15;
    const int quad = lane >> 4;
    const long mblock = (long)blockIdx.x * 64;

    __shared__ u16 Alds[64][264];   // bf16 tile, +8 pad per row

    #pragma unroll
    for (int i = 0; i < 16; ++i) {
        int q = i*256 + tid;
        int r = q >> 6;
        int c = (q & 63) << 2;
        f32x4 a4 = *(const f32x4*)&A[(mblock + r)*256 + c];
        if (COPY_A)
            *(f32x4*)&copyDst[(mblock + r)*256 + c] = a4;
        uint2 val;
        val.x = cvt_pk_bf16(a4[0], a4[1]);
        val.y = cvt_pk_bf16(a4[2], a4[3]);
        *(uint2*)&Alds[r][c] = val;
    }

    s16x8 wfrag[4][8];
    const int nbase = wave * 64;
    #pragma unroll
    for (int nt = 0; nt < 4; ++nt)
        #pragma unroll
        for (int kt = 0; kt < 8; ++kt)
            wfrag[nt][kt] = *(const s16x8*)&WT[(nbase + nt*16 + l15)*256 + kt*32 + quad*8];

    __syncthreads();

    f32x4 acc[4][4] = {};   // [mt][nt]
    #pragma unroll
    for (int kt = 0; kt < 8; ++kt) {
        s16x8 xfrag[4];
        #pragma unroll
        for (int mt = 0; mt < 4; ++mt)
            xfrag[mt] = *(const s16x8*)&Alds[mt*16 + l15][kt*32 + quad*8];
        #pragma unroll
        for (int mt = 0; mt < 4; ++mt)
            #pragma unroll
            for (int nt = 0; nt < 4; ++nt)
                acc[mt][nt] = __builtin_amdgcn_mfma_f32_16x16x32_bf16(
                    wfrag[nt][kt], xfrag[mt], acc[mt][nt], 0, 0, 0);
    }

    #pragma unroll
    for (int mt = 0; mt < 4; ++mt) {
        long m = mblock + mt*16 + l15;
        #pragma unroll
        for (int nt = 0; nt < 4; ++nt) {
            int n = nbase + nt*16 + quad*4;
            f32x4 r = acc[mt][nt];
            if (ADD_BIAS) {
                f32x4 bb = *(const f32x4*)&bias[n];
                r[0] += bb[0]; r[1] += bb[1]; r[2] += bb[2]; r[3] += bb[3];
            }
            *(f32x4*)&C[m*256 + n] = r;
        }
    }
}

// ---------------------------------------------------------------------------
// MFMA recurrence. 4 WGs x 512 thr (8 waves => 2 waves/SIMD); WG = 16 batches.
// Per step: v = alpha*v + xin + s @ W_rec ; s = sigmoid(v).
// Round-1 counters: 1 wave/SIMD (Occupancy 0.19%) left ~1300 cyc/step of
// exposed dependency latency (MFMA chains, exp->add->rcp, post-barrier
// ds_read). This round: each wave owns a 32-wide h slice (nt=2); two
// co-resident waves/SIMD fill each other's stall gaps. Per-CU pipe work is
// unchanged; LDS sfrag BW doubles (64 KB/step/CU ~ 256 cyc) but overlaps.
// Lane holds D[n = nbase+nt*16+quad*4+r][batch = lane&15] (HW-verified r4).
// s ping-pong in LDS (bf16), ONE raw lds_barrier per step; global stores are
// never waited on; xin prefetched 2 steps ahead (unroll-by-2 ping-pong regs);
// only probs written per step (spikes[1:] materialized by gemm2's COPY_A).
// ---------------------------------------------------------------------------
__global__ __launch_bounds__(512, 2)
void recurrence_mfma(const float* __restrict__ Xin, const float* __restrict__ spike0,
                     const float* __restrict__ v0, const u16* __restrict__ WTrec,
                     float* __restrict__ out)
{
    const int tid  = threadIdx.x;
    const int lane = tid & 63;
    const int wave = tid >> 6;          // 0..7
    const int l15  = lane & 15;
    const int quad = lane >> 4;
    const int B0   = blockIdx.x * 16;
    const int nbase = wave * 32;        // 32-wide h slice per wave
    const int hq = quad * 4;

    __shared__ u16 s_lds[2][16][264];     // [buf][batch][h]

    // W_rec^T A-fragments, register-resident for all 512 steps (64 VGPRs)
    s16x8 wfrag[2][8];
    #pragma unroll
    for (int nt = 0; nt < 2; ++nt)
        #pragma unroll
        for (int kt = 0; kt < 8; ++kt)
            wfrag[nt][kt] = *(const s16x8*)&WTrec[(nbase + nt*16 + l15)*256 + kt*32 + quad*8];

    // init s buffer 0 from spike0; emit spikes[0]
    #pragma unroll
    for (int i = 0; i < 8; ++i) {
        int idx = i*512 + tid;
        int m = idx >> 8, h = idx & 255;
        float s0v = spike0[(B0 + m)*256 + h];
        out[SPIKES_OFF + (B0 + m)*256 + h] = s0v;
        s_lds[0][m][h] = f2bf(s0v);
    }

    const long lrow = (long)(B0 + l15) * 256;
    f32x4 v[2], xinA[2], xinB[2];
    #pragma unroll
    for (int nt = 0; nt < 2; ++nt) {
        const int h = nbase + nt*16 + hq;
        v[nt]    = *(const f32x4*)&v0[lrow + h];
        xinA[nt] = *(const f32x4*)&Xin[lrow + h];           // t=0
        xinB[nt] = *(const f32x4*)&Xin[16384 + lrow + h];   // t=1
    }
    // walking pointers: one 64-bit bump (+64 KB) per half-step; nt -> imm offset.
    const float* xin_p = Xin + 2L*16384 + lrow + nbase + hq;   // prefetch t=2
    float*       pr_p  = out + PROBS_OFF + lrow + nbase + hq;  // probs t=0

    __syncthreads();   // one-time full barrier (covers spike0 LDS init)

    #pragma unroll 1
    for (int t2 = 0; t2 < TT; t2 += 2) {
        #pragma unroll
        for (int half = 0; half < 2; ++half) {
            const int rb = half, wb = half ^ 1;   // t2 even -> (t&1) == half

            // issue prefetch for t+2 FIRST (vmcnt decoupling: the consume-wait
            // 2 steps later then tolerates all intervening stores in flight).
            // Final-iteration over-read (t=512,513) lands in the probs region:
            // valid memory, never consumed.
            f32x4 xnew[2];
            #pragma unroll
            for (int nt = 0; nt < 2; ++nt)
                xnew[nt] = *(const f32x4*)&xin_p[nt*16];

            // s B-fragments from LDS: lane: batch=l15, k = kt*32+quad*8+j
            s16x8 sfrag[8];
            #pragma unroll
            for (int kt = 0; kt < 8; ++kt)
                sfrag[kt] = *(const s16x8*)&s_lds[rb][l15][kt*32 + quad*8];

            // acc = alpha*v + xin (consume this step's 2-ahead prefetch)
            f32x4 acc[2];
            #pragma unroll
            for (int nt = 0; nt < 2; ++nt)
                #pragma unroll
                for (int c = 0; c < 4; ++c)
                    acc[nt][c] = fmaf(ALPHA, v[nt][c],
                                      half == 0 ? xinA[nt][c] : xinB[nt][c]);
            #pragma unroll
            for (int nt = 0; nt < 2; ++nt) {
                if (half == 0) xinA[nt] = xnew[nt]; else xinB[nt] = xnew[nt];
            }

            // accumulate s @ W_rec (2 independent chains of 8, hidden by the
            // co-resident wave's MFMAs)
            #pragma unroll
            for (int kt = 0; kt < 8; ++kt)
                #pragma unroll
                for (int nt = 0; nt < 2; ++nt)
                    acc[nt] = __builtin_amdgcn_mfma_f32_16x16x32_bf16(
                        wfrag[nt][kt], sfrag[kt], acc[nt], 0, 0, 0);

            // sigmoid -> s (bf16 to LDS ASAP: it's the inter-step critical
            // path); probs store + v update off-path afterwards.
            f32x4 p[2];
            #pragma unroll
            for (int nt = 0; nt < 2; ++nt) {
                const int h = nbase + nt*16 + hq;
                #pragma unroll
                for (int c = 0; c < 4; ++c)
                    p[nt][c] = __builtin_amdgcn_rcpf(1.0f + __expf(-acc[nt][c]));
                uint2 sw;
                sw.x = cvt_pk_bf16(p[nt][0], p[nt][1]);
                sw.y = cvt_pk_bf16(p[nt][2], p[nt][3]);
                *(uint2*)&s_lds[wb][l15][h] = sw;
            }
            #pragma unroll
            for (int nt = 0; nt < 2; ++nt) {
                v[nt] = acc[nt];
                *(f32x4*)&pr_p[nt*16] = p[nt];
            }
            xin_p += 16384;
            pr_p  += 16384;
            lds_barrier();   // LDS-only: no vmcnt drain of stores/prefetch
        }
    }

    // tails: v_T and s_T = sigmoid(v_T) (recomputed once; no per-step branch)
    #pragma unroll
    for (int nt = 0; nt < 2; ++nt) {
        const int h = nbase + nt*16 + hq;
        f32x4 vv = v[nt], p;
        #pragma unroll
        for (int c = 0; c < 4; ++c)
            p[c] = __builtin_amdgcn_rcpf(1.0f + __expf(-vv[c]));
        *(f32x4*)&out[VT_OFF + lrow + h] = vv;
        *(f32x4*)&out[ST_OFF + lrow + h] = p;
    }
}

// ---------------------------------------------------------------------------
extern "C" void kernel_launch(void* const* d_in, const int* in_sizes, int n_in,
                              void* d_out, int out_size, void* d_ws, size_t ws_size,
                              hipStream_t stream) {
    const float* inputs = (const float*)d_in[0];   // [512,64,256]
    const float* spike0 = (const float*)d_in[1];   // [64,256]
    const float* v0     = (const float*)d_in[2];   // [64,256]
    const float* W_in   = (const float*)d_in[3];   // [256,256]
    const float* W_rec  = (const float*)d_in[4];   // [256,256]
    const float* W_out  = (const float*)d_in[5];   // [256,256]
    const float* bvec   = (const float*)d_in[6];   // [256]
    float* out = (float*)d_out;

    // d_ws: 3 transposed bf16 weight matrices, 384 KB.
    u16* WT = (u16*)d_ws;
    u16* WTin  = WT;
    u16* WTrec = WT + 65536;
    u16* WTout = WT + 131072;

    // Xin (fp32 [32768,256]) staged in the preds output region; overwritten by
    // gemm2 after the recurrence consumes it.
    float* Xin = out + PREDS_OFF;

    transpose_w<<<3, 256, 0, stream>>>(W_in, W_rec, W_out, WT);
    gemm_rows<true, false><<<512, 256, 0, stream>>>(inputs, WTin, bvec, Xin, nullptr);
    recurrence_mfma<<<4, 512, 0, stream>>>(Xin, spike0, v0, WTrec, out);
    // gemm2 reads probs as A (== spikes[1:]) and mirrors the tile into the
    // spikes region while staging it -- recurrence no longer writes spikes.
    gemm_rows<false, true><<<512, 256, 0, stream>>>(out + PROBS_OFF, WTout, bvec,
                                                    out + PREDS_OFF, out + 16384);
}